// Round 8
// baseline (724.813 us; speedup 1.0000x reference)
//
#include <hip/hip_runtime.h>
#include <hip/hip_bf16.h>

#define NN 100000
#define NE 1600000
#define DD 128
#define NL 3
#define NG 512
#define NBLK ((NN + 255) / 256)        // 391 scan blocks
#define CSRP (NE + 8 * NN)             // padded CSR capacity (ints) = 2.4M
#define NBUCK ((NN + 63) / 64)         // 1563 dst-buckets (64 nodes each)

// fused init kernel block ranges (256 threads each)
#define CONV_BLKS 12501                // (NN+1)*DD/4 threads
#define PREPW_BLKS 384                 // NL*2*DD*DD/256
#define DEG_BLKS  391                  // NN/256
#define INIT_BLKS (CONV_BLKS + PREPW_BLKS + DEG_BLKS)

typedef __attribute__((ext_vector_type(8))) short bf16x8;
typedef __attribute__((ext_vector_type(4))) float f32x4;

__device__ __forceinline__ unsigned short f2bf(float f) {
    union { float f; unsigned int u; } x; x.f = f;
    unsigned int r = x.u + 0x7FFFu + ((x.u >> 16) & 1u);
    return (unsigned short)(r >> 16);
}
__device__ __forceinline__ float bf2f(unsigned short u) {
    union { unsigned int u; float f; } x; x.u = ((unsigned int)u) << 16;
    return x.f;
}
__device__ __forceinline__ float bflo(unsigned int v) { return bf2f((unsigned short)(v & 0xffffu)); }
__device__ __forceinline__ float bfhi(unsigned int v) { return bf2f((unsigned short)(v >> 16)); }
__device__ __forceinline__ unsigned cvtpk(float lo, float hi) {
    unsigned r;
    asm("v_cvt_pk_bf16_f32 %0, %1, %2" : "=v"(r) : "v"(lo), "v"(hi));
    return r;
}

// -------- fused init: conv_x | prep_w | deg=0 --------
__global__ __launch_bounds__(256) void init_all(const float* __restrict__ x,
                                                unsigned short* __restrict__ h0,
                                                unsigned short* __restrict__ h1,
                                                const float* __restrict__ W1,
                                                const float* __restrict__ W2,
                                                unsigned short* __restrict__ wbf,
                                                int* __restrict__ deg) {
    int bb = blockIdx.x;
    if (bb < CONV_BLKS) {
        long long t = (long long)bb * 256 + threadIdx.x;
        long long base = t * 4;
        if (base < (long long)NN * DD) {
            float4 v = *reinterpret_cast<const float4*>(x + base);
            ushort4 p;
            p.x = f2bf(v.x); p.y = f2bf(v.y); p.z = f2bf(v.z); p.w = f2bf(v.w);
            *reinterpret_cast<ushort4*>(h0 + base) = p;
        } else if (base < (long long)(NN + 1) * DD) {
            ushort4 z = {0, 0, 0, 0};
            *reinterpret_cast<ushort4*>(h0 + base) = z;
            *reinterpret_cast<ushort4*>(h1 + base) = z;
        }
        return;
    }
    bb -= CONV_BLKS;
    if (bb < PREPW_BLKS) {
        int idx = bb * 256 + threadIdx.x;            // < NL*2*DD*DD
        int k = idx & 127;
        int n = (idx >> 7) & 127;
        int w = (idx >> 14) & 1;
        int l = idx >> 15;
        const float* src = w ? W2 : W1;
        wbf[idx] = f2bf(src[(l * DD + k) * DD + n]);
        return;
    }
    bb -= PREPW_BLKS;
    int i = bb * 256 + threadIdx.x;
    if (i < NN) deg[i] = 0;
}

// ---------------- CSR build (once per call) ----------------
__global__ __launch_bounds__(256) void hist_deg(const int* __restrict__ ei,
                                                int* __restrict__ deg) {
    unsigned int e = blockIdx.x * 256u + threadIdx.x;   // < NE
    atomicAdd(&deg[ei[NE + e]], 1);
}

// scan over PADDED degrees (pdeg = ceil(deg/8)*8) + per-bucket raw-deg sums
// (each 64-lane wave == one 64-node bucket)
__global__ __launch_bounds__(256) void scan1(const int* __restrict__ deg,
                                             int* __restrict__ rp,
                                             int* __restrict__ part,
                                             int* __restrict__ bhist) {
    __shared__ int s[256];
    int tid = threadIdx.x;
    int i = blockIdx.x * 256 + tid;
    int vr = (i < NN) ? deg[i] : 0;
    int v = (vr + 7) & ~7;
    s[tid] = v;
    __syncthreads();
    for (int o = 1; o < 256; o <<= 1) {
        int t = (tid >= o) ? s[tid - o] : 0;
        __syncthreads();
        s[tid] += t;
        __syncthreads();
    }
    if (i < NN) rp[i] = s[tid] - v;
    if (tid == 255) part[blockIdx.x] = s[255];
    // bucket sums of RAW deg: wave-reduce
    int bs = vr;
    #pragma unroll
    for (int o = 1; o < 64; o <<= 1) bs += __shfl_xor(bs, o);
    int bucket = blockIdx.x * 4 + (tid >> 6);
    if ((tid & 63) == 0 && bucket < NBUCK) bhist[bucket] = bs;
}

// merged scan2+scan3: finalize rp, write ONLY pad slots (deg..pdeg) with NN
__global__ __launch_bounds__(256) void scan23(int* __restrict__ rp,
                                              const int* __restrict__ part,
                                              const int* __restrict__ deg,
                                              int* __restrict__ csr) {
    __shared__ int red[256];
    int tid = threadIdx.x;
    int bid = blockIdx.x;
    int s = 0;
    for (int i = tid; i < bid; i += 256) s += part[i];
    red[tid] = s;
    __syncthreads();
    for (int o = 128; o > 0; o >>= 1) {
        if (tid < o) red[tid] += red[tid + o];
        __syncthreads();
    }
    int base = red[0];
    int i = bid * 256 + tid;
    if (i < NN) {
        int val = rp[i] + base;
        rp[i] = val;
        int d = deg[i];
        int pd = (d + 7) & ~7;
        for (int j = val + d; j < val + pd; ++j) csr[j] = NN;
        if (i == NN - 1) rp[NN] = val + pd;
    }
}

// single-block exclusive scan of bhist -> boff (NBUCK+1), zero bpos
__global__ __launch_bounds__(256) void bscan(const int* __restrict__ bhist,
                                             int* __restrict__ boff,
                                             int* __restrict__ bpos) {
    __shared__ int s[256];
    const int PT = (NBUCK + 255) / 256;   // 7
    int tid = threadIdx.x;
    int loc[PT];
    int sum = 0;
    #pragma unroll
    for (int j = 0; j < PT; ++j) {
        int idx = tid * PT + j;
        int v = (idx < NBUCK) ? bhist[idx] : 0;
        loc[j] = sum;
        sum += v;
    }
    s[tid] = sum;
    __syncthreads();
    for (int o = 1; o < 256; o <<= 1) {
        int t = (tid >= o) ? s[tid - o] : 0;
        __syncthreads();
        s[tid] += t;
        __syncthreads();
    }
    int base = s[tid] - sum;   // exclusive
    #pragma unroll
    for (int j = 0; j < PT; ++j) {
        int idx = tid * PT + j;
        if (idx < NBUCK) boff[idx] = base + loc[j];
    }
    if (tid == 0) boff[NBUCK] = NE;
    for (int i = tid; i < NBUCK; i += 256) bpos[i] = 0;
}

// pass A: append packed (src | dlocal<<17) into bucket-ordered ebuf
__global__ __launch_bounds__(256) void bin_scatter(const int* __restrict__ ei,
                                                   const int* __restrict__ boff,
                                                   int* __restrict__ bpos,
                                                   int* __restrict__ ebuf) {
    unsigned int e = blockIdx.x * 256u + threadIdx.x;   // < NE
    int s = ei[e];
    int d = ei[NE + e];
    int b = d >> 6;
    int pos = atomicAdd(&bpos[b], 1);
    ebuf[boff[b] + pos] = s | ((d & 63) << 17);
}

// pass B: one block per bucket; LDS counters + rp cache; csr writes land in
// the bucket's ~4.5 KB contiguous window (single write-back per line)
__global__ __launch_bounds__(256) void fill2(const int* __restrict__ ebuf,
                                             const int* __restrict__ boff,
                                             const int* __restrict__ rp,
                                             int* __restrict__ csr) {
    __shared__ int lcnt[64];
    __shared__ int rpl[64];
    int b = blockIdx.x;
    int tid = threadIdx.x;
    if (tid < 64) {
        int node = b * 64 + tid;
        rpl[tid] = (node < NN) ? rp[node] : 0;
        lcnt[tid] = 0;
    }
    __syncthreads();
    int st = boff[b], en = boff[b + 1];
    for (int i = st + tid; i < en; i += 256) {
        int v = ebuf[i];
        int s = v & 0x1FFFF;
        int dl = v >> 17;
        int pos = atomicAdd(&lcnt[dl], 1);
        csr[rpl[dl] + pos] = s;
    }
}

// ---------------- fused layer: gather-agg + MLP + BN ----------------
__global__ __launch_bounds__(256) void layer_fused(
    const unsigned short* __restrict__ hin,   // (NN+1) rows, row NN = zeros
    const int* __restrict__ rp,               // padded row ptr (8-aligned)
    const int* __restrict__ csr,              // padded neighbor lists
    const unsigned short* __restrict__ w1t,   // [n][k] bf16
    const unsigned short* __restrict__ w2t,   // [n][k] bf16
    const float* __restrict__ b1,
    const float* __restrict__ b2,
    const float* __restrict__ gamma,
    const float* __restrict__ beta,
    const float* __restrict__ rmean,
    const float* __restrict__ rvar,
    const float* __restrict__ epsv,
    unsigned short* __restrict__ hout)
{
    __shared__ unsigned short z_lds[16 * 136];   // 4.35 KB
    const int tid = threadIdx.x;
    const int lane = tid & 63;
    const int wave = tid >> 6;
    const int gid = lane >> 4;        // group 0..3, owns one row
    const int lg = lane & 15;         // 16B feature slice within group
    const int row0 = blockIdx.x * 16;
    const float epl = 1.0f + epsv[0];
    const size_t lgo = (size_t)lg * 8;

#define ACC8(v) do { \
    acc[0] += bflo((v).x); acc[1] += bfhi((v).x); \
    acc[2] += bflo((v).y); acc[3] += bfhi((v).y); \
    acc[4] += bflo((v).z); acc[5] += bfhi((v).z); \
    acc[6] += bflo((v).w); acc[7] += bfhi((v).w); } while (0)

    // Phase 1: gather-aggregate; group g of wave w owns row w*4+g
    const int rbase = row0 + (wave << 2);
    int pv = (lane < 5) ? rp[rbase + lane] : 0;   // 5 rowptrs
    const int st = __shfl(pv, gid);
    const int en = __shfl(pv, gid + 1);
    const int myrow = rbase + gid;

    float acc[8];
    {
        uint4 sv = *reinterpret_cast<const uint4*>(hin + (size_t)myrow * DD + lgo);
        acc[0] = epl * bflo(sv.x); acc[1] = epl * bfhi(sv.x);
        acc[2] = epl * bflo(sv.y); acc[3] = epl * bfhi(sv.y);
        acc[4] = epl * bflo(sv.z); acc[5] = epl * bfhi(sv.z);
        acc[6] = epl * bflo(sv.w); acc[7] = epl * bfhi(sv.w);
    }
    for (int c0 = st; c0 < en; c0 += 8) {
        int4 idA = *reinterpret_cast<const int4*>(csr + c0);
        int4 idB = *reinterpret_cast<const int4*>(csr + c0 + 4);
        uint4 v0 = *reinterpret_cast<const uint4*>(hin + (size_t)idA.x * DD + lgo);
        uint4 v1 = *reinterpret_cast<const uint4*>(hin + (size_t)idA.y * DD + lgo);
        uint4 v2 = *reinterpret_cast<const uint4*>(hin + (size_t)idA.z * DD + lgo);
        uint4 v3 = *reinterpret_cast<const uint4*>(hin + (size_t)idA.w * DD + lgo);
        uint4 v4 = *reinterpret_cast<const uint4*>(hin + (size_t)idB.x * DD + lgo);
        uint4 v5 = *reinterpret_cast<const uint4*>(hin + (size_t)idB.y * DD + lgo);
        uint4 v6 = *reinterpret_cast<const uint4*>(hin + (size_t)idB.z * DD + lgo);
        uint4 v7 = *reinterpret_cast<const uint4*>(hin + (size_t)idB.w * DD + lgo);
        ACC8(v0); ACC8(v1); ACC8(v2); ACC8(v3);
        ACC8(v4); ACC8(v5); ACC8(v6); ACC8(v7);
    }
    {
        uint4 pk;
        pk.x = cvtpk(acc[0], acc[1]);
        pk.y = cvtpk(acc[2], acc[3]);
        pk.z = cvtpk(acc[4], acc[5]);
        pk.w = cvtpk(acc[6], acc[7]);
        *reinterpret_cast<uint4*>(&z_lds[((wave << 2) + gid) * 136 + lg * 8]) = pk;
    }
    __syncthreads();

    const int l15 = lane & 15;
    const int kq = lane >> 4;
    const int colbase = wave << 5;     // 32-col slice per wave

    // Matmul 1 (B-fragments straight from global; 32 KB weight is L1/L2-hot)
    bf16x8 afr[4];
    #pragma unroll
    for (int kk = 0; kk < 4; ++kk)
        afr[kk] = *reinterpret_cast<const bf16x8*>(&z_lds[l15 * 136 + kk * 32 + kq * 8]);

    f32x4 acc4[2];
    #pragma unroll
    for (int nt = 0; nt < 2; ++nt) acc4[nt] = (f32x4){0.f, 0.f, 0.f, 0.f};
    #pragma unroll
    for (int nt = 0; nt < 2; ++nt) {
        #pragma unroll
        for (int kk = 0; kk < 4; ++kk) {
            bf16x8 bfr = *reinterpret_cast<const bf16x8*>(
                w1t + (colbase + nt * 16 + l15) * DD + kk * 32 + kq * 8);
            acc4[nt] = __builtin_amdgcn_mfma_f32_16x16x32_bf16(afr[kk], bfr, acc4[nt], 0, 0, 0);
        }
    }
    __syncthreads();   // all afr reads done before epi1 writes

    // Epilogue 1: bias+relu, z1 -> z_lds (own 32-col slice, rows 0..15)
    #pragma unroll
    for (int nt = 0; nt < 2; ++nt) {
        int col = colbase + nt * 16 + l15;
        float bv = b1[col];
        #pragma unroll
        for (int r = 0; r < 4; ++r) {
            int zr = kq * 4 + r;
            float v = acc4[nt][r] + bv;
            v = v > 0.f ? v : 0.f;
            z_lds[zr * 136 + col] = f2bf(v);
        }
    }
    __syncthreads();

    // Matmul 2
    #pragma unroll
    for (int kk = 0; kk < 4; ++kk)
        afr[kk] = *reinterpret_cast<const bf16x8*>(&z_lds[l15 * 136 + kk * 32 + kq * 8]);
    #pragma unroll
    for (int nt = 0; nt < 2; ++nt) acc4[nt] = (f32x4){0.f, 0.f, 0.f, 0.f};
    #pragma unroll
    for (int nt = 0; nt < 2; ++nt) {
        #pragma unroll
        for (int kk = 0; kk < 4; ++kk) {
            bf16x8 bfr = *reinterpret_cast<const bf16x8*>(
                w2t + (colbase + nt * 16 + l15) * DD + kk * 32 + kq * 8);
            acc4[nt] = __builtin_amdgcn_mfma_f32_16x16x32_bf16(afr[kk], bfr, acc4[nt], 0, 0, 0);
        }
    }

    // Epilogue 2: bias+relu+BN -> hout (bf16); rows always < NN (no tail)
    #pragma unroll
    for (int nt = 0; nt < 2; ++nt) {
        int col = colbase + nt * 16 + l15;
        float bv = b2[col];
        float ga = gamma[col];
        float be = beta[col];
        float mu = rmean[col];
        float inv = rsqrtf(rvar[col] + 1e-5f);
        #pragma unroll
        for (int r = 0; r < 4; ++r) {
            int zr = kq * 4 + r;
            float v = acc4[nt][r] + bv;
            v = v > 0.f ? v : 0.f;
            v = (v - mu) * inv * ga + be;
            hout[(size_t)(row0 + zr) * DD + col] = f2bf(v);
        }
    }
#undef ACC8
}

// ---------------- pool (sorted batch -> segment sums) + final linear ----------------
__global__ __launch_bounds__(256) void pool_final(const unsigned short* __restrict__ h,
                                                  const int* __restrict__ batch,
                                                  const float* __restrict__ W,
                                                  const float* __restrict__ b,
                                                  float* __restrict__ out) {
    int g = blockIdx.x;           // one block per graph
    int t = threadIdx.x;
    int c2 = t & 63;              // col pair 2*c2, 2*c2+1
    int qu = t >> 6;              // row strand 0..3

    int lo = 0, hi = NN;
    while (lo < hi) { int mid = (lo + hi) >> 1; if (batch[mid] < g) lo = mid + 1; else hi = mid; }
    int start = lo;
    hi = NN;
    while (lo < hi) { int mid = (lo + hi) >> 1; if (batch[mid] < g + 1) lo = mid + 1; else hi = mid; }
    int end = lo;

    float ax = 0.f, ay = 0.f;
    for (int i = start + qu; i < end; i += 4) {
        unsigned u = *reinterpret_cast<const unsigned*>(h + (size_t)i * DD + c2 * 2);
        ax += bflo(u); ay += bfhi(u);
    }

    __shared__ float ps[4][DD];
    ps[qu][c2 * 2] = ax;
    ps[qu][c2 * 2 + 1] = ay;
    __syncthreads();
    if (t < DD) {
        float inv = 1.0f / fmaxf((float)(end - start), 1.0f);
        ps[0][t] = (ps[0][t] + ps[1][t] + ps[2][t] + ps[3][t]) * inv;
    }
    __syncthreads();
    if (t < DD) {
        float o = b[t];
        #pragma unroll 8
        for (int k = 0; k < DD; ++k)
            o += ps[0][k] * W[k * DD + t];
        out[(size_t)g * DD + t] = fmaxf(o, 0.f);
    }
}

extern "C" void kernel_launch(void* const* d_in, const int* in_sizes, int n_in,
                              void* d_out, int out_size, void* d_ws, size_t ws_size,
                              hipStream_t stream) {
    const float* x     = (const float*)d_in[0];
    const int*   ei    = (const int*)d_in[1];
    const int*   batch = (const int*)d_in[2];
    const float* W1    = (const float*)d_in[3];
    const float* b1    = (const float*)d_in[4];
    const float* W2    = (const float*)d_in[5];
    const float* b2    = (const float*)d_in[6];
    const float* gamma = (const float*)d_in[7];
    const float* beta  = (const float*)d_in[8];
    const float* rmean = (const float*)d_in[9];
    const float* rvar  = (const float*)d_in[10];
    const float* eps   = (const float*)d_in[11];
    const float* lin1W = (const float*)d_in[12];
    const float* lin1b = (const float*)d_in[13];
    float* out = (float*)d_out;

    char* ws = (char*)d_ws;
    size_t off = 0;
    auto alloc = [&](size_t bytes) {
        void* p = ws + off;
        off = (off + bytes + 255) & ~(size_t)255;
        return p;
    };
    unsigned short* h0  = (unsigned short*)alloc((size_t)(NN + 1) * DD * 2);
    unsigned short* h1  = (unsigned short*)alloc((size_t)(NN + 1) * DD * 2);
    int* rp    = (int*)alloc((size_t)(NN + 1) * 4);
    int* deg   = (int*)alloc((size_t)NN * 4);
    int* part  = (int*)alloc(512 * 4);
    int* bhist = (int*)alloc((size_t)NBUCK * 4);
    int* boff  = (int*)alloc((size_t)(NBUCK + 1) * 4);
    int* bpos  = (int*)alloc((size_t)NBUCK * 4);
    int* csr   = (int*)alloc((size_t)CSRP * 4);
    int* ebuf  = (int*)alloc((size_t)NE * 4);
    unsigned short* wbf = (unsigned short*)alloc((size_t)NL * 2 * DD * DD * 2);

    init_all<<<INIT_BLKS, 256, 0, stream>>>(x, h0, h1, W1, W2, wbf, deg);

    hist_deg<<<NE / 256, 256, 0, stream>>>(ei, deg);
    scan1<<<NBLK, 256, 0, stream>>>(deg, rp, part, bhist);
    scan23<<<NBLK, 256, 0, stream>>>(rp, part, deg, csr);
    bscan<<<1, 256, 0, stream>>>(bhist, boff, bpos);
    bin_scatter<<<NE / 256, 256, 0, stream>>>(ei, boff, bpos, ebuf);
    fill2<<<NBUCK, 256, 0, stream>>>(ebuf, boff, rp, csr);

    const int lgrid = NN / 16;   // 6250, exact
    layer_fused<<<lgrid, 256, 0, stream>>>(
        h0, rp, csr, wbf + 0 * DD * DD, wbf + 1 * DD * DD,
        b1 + 0 * DD, b2 + 0 * DD, gamma + 0 * DD, beta + 0 * DD,
        rmean + 0 * DD, rvar + 0 * DD, eps + 0, h1);
    layer_fused<<<lgrid, 256, 0, stream>>>(
        h1, rp, csr, wbf + 2 * DD * DD, wbf + 3 * DD * DD,
        b1 + 1 * DD, b2 + 1 * DD, gamma + 1 * DD, beta + 1 * DD,
        rmean + 1 * DD, rvar + 1 * DD, eps + 1, h0);
    layer_fused<<<lgrid, 256, 0, stream>>>(
        h0, rp, csr, wbf + 4 * DD * DD, wbf + 5 * DD * DD,
        b1 + 2 * DD, b2 + 2 * DD, gamma + 2 * DD, beta + 2 * DD,
        rmean + 2 * DD, rvar + 2 * DD, eps + 2, h1);

    pool_final<<<NG, 256, 0, stream>>>(h1, batch, lin1W, lin1b, out);
}

// Round 9
// 519.203 us; speedup vs baseline: 1.3960x; 1.3960x over previous
//
#include <hip/hip_runtime.h>
#include <hip/hip_bf16.h>

#define NN 100000
#define NE 1600000
#define DD 128
#define NL 3
#define NG 512
#define NBLK ((NN + 255) / 256)        // 391 scan blocks
#define CSRP (NE + 8 * NN)             // padded CSR capacity (ints) = 2.4M
#define NBUCK ((NN + 63) / 64)         // 1563 fine buckets (64 nodes)
#define BSHIFT 9                       // coarse bucket = 512 nodes
#define NBUCK2 ((NN + 511) / 512)      // 196 coarse buckets
#define ABLKS 512
#define ECHUNK (NE / ABLKS)            // 3125 edges per binA block (exact)

// fused init kernel block ranges (256 threads each)
#define CONV_BLKS 12501                // (NN+1)*DD/4 threads
#define PREPW_BLKS 384                 // NL*2*DD*DD/256
#define DEG_BLKS  391                  // NN/256
#define INIT_BLKS (CONV_BLKS + PREPW_BLKS + DEG_BLKS)

typedef __attribute__((ext_vector_type(8))) short bf16x8;
typedef __attribute__((ext_vector_type(4))) float f32x4;

__device__ __forceinline__ unsigned short f2bf(float f) {
    union { float f; unsigned int u; } x; x.f = f;
    unsigned int r = x.u + 0x7FFFu + ((x.u >> 16) & 1u);
    return (unsigned short)(r >> 16);
}
__device__ __forceinline__ float bf2f(unsigned short u) {
    union { unsigned int u; float f; } x; x.u = ((unsigned int)u) << 16;
    return x.f;
}
__device__ __forceinline__ float bflo(unsigned int v) { return bf2f((unsigned short)(v & 0xffffu)); }
__device__ __forceinline__ float bfhi(unsigned int v) { return bf2f((unsigned short)(v >> 16)); }
__device__ __forceinline__ unsigned cvtpk(float lo, float hi) {
    unsigned r;
    asm("v_cvt_pk_bf16_f32 %0, %1, %2" : "=v"(r) : "v"(lo), "v"(hi));
    return r;
}

// -------- fused init: conv_x | prep_w | deg=0 --------
__global__ __launch_bounds__(256) void init_all(const float* __restrict__ x,
                                                unsigned short* __restrict__ h0,
                                                unsigned short* __restrict__ h1,
                                                const float* __restrict__ W1,
                                                const float* __restrict__ W2,
                                                unsigned short* __restrict__ wbf,
                                                int* __restrict__ deg) {
    int bb = blockIdx.x;
    if (bb < CONV_BLKS) {
        long long t = (long long)bb * 256 + threadIdx.x;
        long long base = t * 4;
        if (base < (long long)NN * DD) {
            float4 v = *reinterpret_cast<const float4*>(x + base);
            ushort4 p;
            p.x = f2bf(v.x); p.y = f2bf(v.y); p.z = f2bf(v.z); p.w = f2bf(v.w);
            *reinterpret_cast<ushort4*>(h0 + base) = p;
        } else if (base < (long long)(NN + 1) * DD) {
            ushort4 z = {0, 0, 0, 0};
            *reinterpret_cast<ushort4*>(h0 + base) = z;
            *reinterpret_cast<ushort4*>(h1 + base) = z;
        }
        return;
    }
    bb -= CONV_BLKS;
    if (bb < PREPW_BLKS) {
        int idx = bb * 256 + threadIdx.x;            // < NL*2*DD*DD
        int k = idx & 127;
        int n = (idx >> 7) & 127;
        int w = (idx >> 14) & 1;
        int l = idx >> 15;
        const float* src = w ? W2 : W1;
        wbf[idx] = f2bf(src[(l * DD + k) * DD + n]);
        return;
    }
    bb -= PREPW_BLKS;
    int i = bb * 256 + threadIdx.x;
    if (i < NN) deg[i] = 0;
}

// ---------------- CSR build (once per call) ----------------
__global__ __launch_bounds__(256) void hist_deg(const int* __restrict__ ei,
                                                int* __restrict__ deg) {
    unsigned int e = blockIdx.x * 256u + threadIdx.x;   // < NE
    atomicAdd(&deg[ei[NE + e]], 1);
}

// scan over PADDED degrees (pdeg = ceil(deg/8)*8) + fine 64-node bucket sums
__global__ __launch_bounds__(256) void scan1(const int* __restrict__ deg,
                                             int* __restrict__ rp,
                                             int* __restrict__ part,
                                             int* __restrict__ bhist) {
    __shared__ int s[256];
    int tid = threadIdx.x;
    int i = blockIdx.x * 256 + tid;
    int vr = (i < NN) ? deg[i] : 0;
    int v = (vr + 7) & ~7;
    s[tid] = v;
    __syncthreads();
    for (int o = 1; o < 256; o <<= 1) {
        int t = (tid >= o) ? s[tid - o] : 0;
        __syncthreads();
        s[tid] += t;
        __syncthreads();
    }
    if (i < NN) rp[i] = s[tid] - v;
    if (tid == 255) part[blockIdx.x] = s[255];
    // fine-bucket sums of RAW deg: wave-reduce
    int bs = vr;
    #pragma unroll
    for (int o = 1; o < 64; o <<= 1) bs += __shfl_xor(bs, o);
    int bucket = blockIdx.x * 4 + (tid >> 6);
    if ((tid & 63) == 0 && bucket < NBUCK) bhist[bucket] = bs;
}

// merged scan2+scan3: finalize rp, write ONLY pad slots (deg..pdeg) with NN
__global__ __launch_bounds__(256) void scan23(int* __restrict__ rp,
                                              const int* __restrict__ part,
                                              const int* __restrict__ deg,
                                              int* __restrict__ csr) {
    __shared__ int red[256];
    int tid = threadIdx.x;
    int bid = blockIdx.x;
    int s = 0;
    for (int i = tid; i < bid; i += 256) s += part[i];
    red[tid] = s;
    __syncthreads();
    for (int o = 128; o > 0; o >>= 1) {
        if (tid < o) red[tid] += red[tid + o];
        __syncthreads();
    }
    int base = red[0];
    int i = bid * 256 + tid;
    if (i < NN) {
        int val = rp[i] + base;
        rp[i] = val;
        int d = deg[i];
        int pd = (d + 7) & ~7;
        for (int j = val + d; j < val + pd; ++j) csr[j] = NN;
        if (i == NN - 1) rp[NN] = val + pd;
    }
}

// coarse-bucket exclusive scan (from fine bhist, 8:1) -> cboff; zero gpos
__global__ __launch_bounds__(256) void bscan(const int* __restrict__ bhist,
                                             int* __restrict__ cboff,
                                             int* __restrict__ gpos) {
    __shared__ int s[256];
    int tid = threadIdx.x;
    int sum = 0;
    if (tid < NBUCK2) {
        #pragma unroll
        for (int j = 0; j < 8; ++j) {
            int f = tid * 8 + j;
            if (f < NBUCK) sum += bhist[f];
        }
    }
    s[tid] = sum;
    __syncthreads();
    for (int o = 1; o < 256; o <<= 1) {
        int t = (tid >= o) ? s[tid - o] : 0;
        __syncthreads();
        s[tid] += t;
        __syncthreads();
    }
    if (tid < NBUCK2) {
        cboff[tid] = s[tid] - sum;
        gpos[tid] = 0;
    }
    if (tid == 0) cboff[NBUCK2] = NE;
}

// pass A: block-staged binning. LDS histogram -> one global reservation per
// (block,bucket) -> scatter as contiguous runs. Packed: src | dlocal<<17.
__global__ __launch_bounds__(256) void binA(const int* __restrict__ ei,
                                            const int* __restrict__ cboff,
                                            int* __restrict__ gpos,
                                            int* __restrict__ ebuf) {
    __shared__ int hist[NBUCK2];
    __shared__ int sbase[NBUCK2];
    int tid = threadIdx.x;
    int e0 = blockIdx.x * ECHUNK;
    for (int i = tid; i < NBUCK2; i += 256) hist[i] = 0;
    __syncthreads();
    for (int i = tid; i < ECHUNK; i += 256) {
        int d = ei[NE + e0 + i];
        atomicAdd(&hist[d >> BSHIFT], 1);
    }
    __syncthreads();
    for (int i = tid; i < NBUCK2; i += 256) {
        int h = hist[i];
        sbase[i] = (h > 0) ? atomicAdd(&gpos[i], h) : 0;
        hist[i] = 0;    // reuse as cursor
    }
    __syncthreads();
    for (int i = tid; i < ECHUNK; i += 256) {
        int s2 = ei[e0 + i];
        int d = ei[NE + e0 + i];
        int b = d >> BSHIFT;
        int pos = atomicAdd(&hist[b], 1);
        ebuf[cboff[b] + sbase[b] + pos] = s2 | ((d & 511) << 17);
    }
}

// pass B: one block per coarse bucket; csr writes confined to this bucket's
// contiguous window (single writer per line). LDS counters + rp cache.
__global__ __launch_bounds__(256) void binB(const int* __restrict__ ebuf,
                                            const int* __restrict__ cboff,
                                            const int* __restrict__ rp,
                                            int* __restrict__ csr) {
    __shared__ int lcnt[512];
    __shared__ int rpl[512];
    int b = blockIdx.x;
    int tid = threadIdx.x;
    int nb = b << BSHIFT;
    for (int i = tid; i < 512; i += 256) {
        int node = nb + i;
        rpl[i] = (node < NN) ? rp[node] : 0;
        lcnt[i] = 0;
    }
    __syncthreads();
    int st = cboff[b], en = cboff[b + 1];
    for (int i = st + tid; i < en; i += 256) {
        int v = ebuf[i];
        int s2 = v & 0x1FFFF;
        int dl = v >> 17;
        int pos = atomicAdd(&lcnt[dl], 1);
        csr[rpl[dl] + pos] = s2;
    }
}

// ---------------- fused layer: gather-agg + MLP + BN ----------------
__global__ __launch_bounds__(256) void layer_fused(
    const unsigned short* __restrict__ hin,   // (NN+1) rows, row NN = zeros
    const int* __restrict__ rp,               // padded row ptr (8-aligned)
    const int* __restrict__ csr,              // padded neighbor lists
    const unsigned short* __restrict__ w1t,   // [n][k] bf16
    const unsigned short* __restrict__ w2t,   // [n][k] bf16
    const float* __restrict__ b1,
    const float* __restrict__ b2,
    const float* __restrict__ gamma,
    const float* __restrict__ beta,
    const float* __restrict__ rmean,
    const float* __restrict__ rvar,
    const float* __restrict__ epsv,
    unsigned short* __restrict__ hout)
{
    __shared__ unsigned short z_lds[16 * 136];   // 4.35 KB
    const int tid = threadIdx.x;
    const int lane = tid & 63;
    const int wave = tid >> 6;
    const int gid = lane >> 4;        // group 0..3, owns one row
    const int lg = lane & 15;         // 16B feature slice within group
    const int row0 = blockIdx.x * 16;
    const float epl = 1.0f + epsv[0];
    const size_t lgo = (size_t)lg * 8;

#define ACC8(v) do { \
    acc[0] += bflo((v).x); acc[1] += bfhi((v).x); \
    acc[2] += bflo((v).y); acc[3] += bfhi((v).y); \
    acc[4] += bflo((v).z); acc[5] += bfhi((v).z); \
    acc[6] += bflo((v).w); acc[7] += bfhi((v).w); } while (0)

    // Phase 1: gather-aggregate; group g of wave w owns row w*4+g
    const int rbase = row0 + (wave << 2);
    int pv = (lane < 5) ? rp[rbase + lane] : 0;   // 5 rowptrs
    const int st = __shfl(pv, gid);
    const int en = __shfl(pv, gid + 1);
    const int myrow = rbase + gid;

    float acc[8];
    {
        uint4 sv = *reinterpret_cast<const uint4*>(hin + (size_t)myrow * DD + lgo);
        acc[0] = epl * bflo(sv.x); acc[1] = epl * bfhi(sv.x);
        acc[2] = epl * bflo(sv.y); acc[3] = epl * bfhi(sv.y);
        acc[4] = epl * bflo(sv.z); acc[5] = epl * bfhi(sv.z);
        acc[6] = epl * bflo(sv.w); acc[7] = epl * bfhi(sv.w);
    }
    for (int c0 = st; c0 < en; c0 += 8) {
        int4 idA = *reinterpret_cast<const int4*>(csr + c0);
        int4 idB = *reinterpret_cast<const int4*>(csr + c0 + 4);
        uint4 v0 = *reinterpret_cast<const uint4*>(hin + (size_t)idA.x * DD + lgo);
        uint4 v1 = *reinterpret_cast<const uint4*>(hin + (size_t)idA.y * DD + lgo);
        uint4 v2 = *reinterpret_cast<const uint4*>(hin + (size_t)idA.z * DD + lgo);
        uint4 v3 = *reinterpret_cast<const uint4*>(hin + (size_t)idA.w * DD + lgo);
        uint4 v4 = *reinterpret_cast<const uint4*>(hin + (size_t)idB.x * DD + lgo);
        uint4 v5 = *reinterpret_cast<const uint4*>(hin + (size_t)idB.y * DD + lgo);
        uint4 v6 = *reinterpret_cast<const uint4*>(hin + (size_t)idB.z * DD + lgo);
        uint4 v7 = *reinterpret_cast<const uint4*>(hin + (size_t)idB.w * DD + lgo);
        ACC8(v0); ACC8(v1); ACC8(v2); ACC8(v3);
        ACC8(v4); ACC8(v5); ACC8(v6); ACC8(v7);
    }
    {
        uint4 pk;
        pk.x = cvtpk(acc[0], acc[1]);
        pk.y = cvtpk(acc[2], acc[3]);
        pk.z = cvtpk(acc[4], acc[5]);
        pk.w = cvtpk(acc[6], acc[7]);
        *reinterpret_cast<uint4*>(&z_lds[((wave << 2) + gid) * 136 + lg * 8]) = pk;
    }
    __syncthreads();

    const int l15 = lane & 15;
    const int kq = lane >> 4;
    const int colbase = wave << 5;     // 32-col slice per wave

    // afr reads of z tile, then barrier (lets epi1 overlap others' MFMA1)
    bf16x8 afr[4];
    #pragma unroll
    for (int kk = 0; kk < 4; ++kk)
        afr[kk] = *reinterpret_cast<const bf16x8*>(&z_lds[l15 * 136 + kk * 32 + kq * 8]);
    __syncthreads();

    // Matmul 1 (B-fragments straight from global; 32 KB weight is L1/L2-hot)
    f32x4 acc4[2];
    #pragma unroll
    for (int nt = 0; nt < 2; ++nt) acc4[nt] = (f32x4){0.f, 0.f, 0.f, 0.f};
    #pragma unroll
    for (int nt = 0; nt < 2; ++nt) {
        #pragma unroll
        for (int kk = 0; kk < 4; ++kk) {
            bf16x8 bfr = *reinterpret_cast<const bf16x8*>(
                w1t + (colbase + nt * 16 + l15) * DD + kk * 32 + kq * 8);
            acc4[nt] = __builtin_amdgcn_mfma_f32_16x16x32_bf16(afr[kk], bfr, acc4[nt], 0, 0, 0);
        }
    }

    // Epilogue 1: bias+relu, z1 -> z_lds (own 32-col slice, rows 0..15)
    #pragma unroll
    for (int nt = 0; nt < 2; ++nt) {
        int col = colbase + nt * 16 + l15;
        float bv = b1[col];
        #pragma unroll
        for (int r = 0; r < 4; ++r) {
            int zr = kq * 4 + r;
            float v = acc4[nt][r] + bv;
            v = v > 0.f ? v : 0.f;
            z_lds[zr * 136 + col] = f2bf(v);
        }
    }
    __syncthreads();

    // Matmul 2
    #pragma unroll
    for (int kk = 0; kk < 4; ++kk)
        afr[kk] = *reinterpret_cast<const bf16x8*>(&z_lds[l15 * 136 + kk * 32 + kq * 8]);
    #pragma unroll
    for (int nt = 0; nt < 2; ++nt) acc4[nt] = (f32x4){0.f, 0.f, 0.f, 0.f};
    #pragma unroll
    for (int nt = 0; nt < 2; ++nt) {
        #pragma unroll
        for (int kk = 0; kk < 4; ++kk) {
            bf16x8 bfr = *reinterpret_cast<const bf16x8*>(
                w2t + (colbase + nt * 16 + l15) * DD + kk * 32 + kq * 8);
            acc4[nt] = __builtin_amdgcn_mfma_f32_16x16x32_bf16(afr[kk], bfr, acc4[nt], 0, 0, 0);
        }
    }

    // Epilogue 2: bias+relu+BN -> hout (bf16); rows always < NN (no tail)
    #pragma unroll
    for (int nt = 0; nt < 2; ++nt) {
        int col = colbase + nt * 16 + l15;
        float bv = b2[col];
        float ga = gamma[col];
        float be = beta[col];
        float mu = rmean[col];
        float inv = rsqrtf(rvar[col] + 1e-5f);
        #pragma unroll
        for (int r = 0; r < 4; ++r) {
            int zr = kq * 4 + r;
            float v = acc4[nt][r] + bv;
            v = v > 0.f ? v : 0.f;
            v = (v - mu) * inv * ga + be;
            hout[(size_t)(row0 + zr) * DD + col] = f2bf(v);
        }
    }
#undef ACC8
}

// ---------------- pool (sorted batch -> segment sums) + final linear ----------------
__global__ __launch_bounds__(256) void pool_final(const unsigned short* __restrict__ h,
                                                  const int* __restrict__ batch,
                                                  const float* __restrict__ W,
                                                  const float* __restrict__ b,
                                                  float* __restrict__ out) {
    int g = blockIdx.x;           // one block per graph
    int t = threadIdx.x;
    int c2 = t & 63;              // col pair 2*c2, 2*c2+1
    int qu = t >> 6;              // row strand 0..3

    int lo = 0, hi = NN;
    while (lo < hi) { int mid = (lo + hi) >> 1; if (batch[mid] < g) lo = mid + 1; else hi = mid; }
    int start = lo;
    hi = NN;
    while (lo < hi) { int mid = (lo + hi) >> 1; if (batch[mid] < g + 1) lo = mid + 1; else hi = mid; }
    int end = lo;

    float ax = 0.f, ay = 0.f;
    for (int i = start + qu; i < end; i += 4) {
        unsigned u = *reinterpret_cast<const unsigned*>(h + (size_t)i * DD + c2 * 2);
        ax += bflo(u); ay += bfhi(u);
    }

    __shared__ float ps[4][DD];
    ps[qu][c2 * 2] = ax;
    ps[qu][c2 * 2 + 1] = ay;
    __syncthreads();
    if (t < DD) {
        float inv = 1.0f / fmaxf((float)(end - start), 1.0f);
        ps[0][t] = (ps[0][t] + ps[1][t] + ps[2][t] + ps[3][t]) * inv;
    }
    __syncthreads();
    if (t < DD) {
        float o = b[t];
        #pragma unroll 8
        for (int k = 0; k < DD; ++k)
            o += ps[0][k] * W[k * DD + t];
        out[(size_t)g * DD + t] = fmaxf(o, 0.f);
    }
}

extern "C" void kernel_launch(void* const* d_in, const int* in_sizes, int n_in,
                              void* d_out, int out_size, void* d_ws, size_t ws_size,
                              hipStream_t stream) {
    const float* x     = (const float*)d_in[0];
    const int*   ei    = (const int*)d_in[1];
    const int*   batch = (const int*)d_in[2];
    const float* W1    = (const float*)d_in[3];
    const float* b1    = (const float*)d_in[4];
    const float* W2    = (const float*)d_in[5];
    const float* b2    = (const float*)d_in[6];
    const float* gamma = (const float*)d_in[7];
    const float* beta  = (const float*)d_in[8];
    const float* rmean = (const float*)d_in[9];
    const float* rvar  = (const float*)d_in[10];
    const float* eps   = (const float*)d_in[11];
    const float* lin1W = (const float*)d_in[12];
    const float* lin1b = (const float*)d_in[13];
    float* out = (float*)d_out;

    char* ws = (char*)d_ws;
    size_t off = 0;
    auto alloc = [&](size_t bytes) {
        void* p = ws + off;
        off = (off + bytes + 255) & ~(size_t)255;
        return p;
    };
    unsigned short* h0  = (unsigned short*)alloc((size_t)(NN + 1) * DD * 2);
    unsigned short* h1  = (unsigned short*)alloc((size_t)(NN + 1) * DD * 2);
    int* rp    = (int*)alloc((size_t)(NN + 1) * 4);
    int* deg   = (int*)alloc((size_t)NN * 4);
    int* part  = (int*)alloc(512 * 4);
    int* bhist = (int*)alloc((size_t)NBUCK * 4);
    int* cboff = (int*)alloc((size_t)(NBUCK2 + 1) * 4);
    int* gpos  = (int*)alloc((size_t)NBUCK2 * 4);
    int* csr   = (int*)alloc((size_t)CSRP * 4);
    int* ebuf  = (int*)alloc((size_t)NE * 4);
    unsigned short* wbf = (unsigned short*)alloc((size_t)NL * 2 * DD * DD * 2);

    init_all<<<INIT_BLKS, 256, 0, stream>>>(x, h0, h1, W1, W2, wbf, deg);

    hist_deg<<<NE / 256, 256, 0, stream>>>(ei, deg);
    scan1<<<NBLK, 256, 0, stream>>>(deg, rp, part, bhist);
    scan23<<<NBLK, 256, 0, stream>>>(rp, part, deg, csr);
    bscan<<<1, 256, 0, stream>>>(bhist, cboff, gpos);
    binA<<<ABLKS, 256, 0, stream>>>(ei, cboff, gpos, ebuf);
    binB<<<NBUCK2, 256, 0, stream>>>(ebuf, cboff, rp, csr);

    const int lgrid = NN / 16;   // 6250, exact
    layer_fused<<<lgrid, 256, 0, stream>>>(
        h0, rp, csr, wbf + 0 * DD * DD, wbf + 1 * DD * DD,
        b1 + 0 * DD, b2 + 0 * DD, gamma + 0 * DD, beta + 0 * DD,
        rmean + 0 * DD, rvar + 0 * DD, eps + 0, h1);
    layer_fused<<<lgrid, 256, 0, stream>>>(
        h1, rp, csr, wbf + 2 * DD * DD, wbf + 3 * DD * DD,
        b1 + 1 * DD, b2 + 1 * DD, gamma + 1 * DD, beta + 1 * DD,
        rmean + 1 * DD, rvar + 1 * DD, eps + 1, h0);
    layer_fused<<<lgrid, 256, 0, stream>>>(
        h0, rp, csr, wbf + 4 * DD * DD, wbf + 5 * DD * DD,
        b1 + 2 * DD, b2 + 2 * DD, gamma + 2 * DD, beta + 2 * DD,
        rmean + 2 * DD, rvar + 2 * DD, eps + 2, h1);

    pool_final<<<NG, 256, 0, stream>>>(h1, batch, lin1W, lin1b, out);
}

// Round 10
// 473.477 us; speedup vs baseline: 1.5308x; 1.0966x over previous
//
#include <hip/hip_runtime.h>
#include <hip/hip_bf16.h>

#define NN 100000
#define NE 1600000
#define DD 128
#define NL 3
#define NG 512
#define CSRP (NE + 8 * NN)             // padded CSR capacity (ints) = 2.4M
#define BSHIFT 9                       // coarse bucket = 512 nodes
#define NBUCK2 ((NN + 511) / 512)      // 196 coarse buckets
#define ABLKS 512
#define ECHUNK (NE / ABLKS)            // 3125 edges per binA block (exact)

// fused init kernel block ranges (256 threads each)
#define CONV_BLKS 12501                // (NN+1)*DD/4 threads
#define PREPW_BLKS 384                 // NL*2*DD*DD/256
#define INIT_BLKS (CONV_BLKS + PREPW_BLKS + 1)

typedef __attribute__((ext_vector_type(8))) short bf16x8;
typedef __attribute__((ext_vector_type(4))) float f32x4;

__device__ __forceinline__ unsigned short f2bf(float f) {
    union { float f; unsigned int u; } x; x.f = f;
    unsigned int r = x.u + 0x7FFFu + ((x.u >> 16) & 1u);
    return (unsigned short)(r >> 16);
}
__device__ __forceinline__ float bf2f(unsigned short u) {
    union { unsigned int u; float f; } x; x.u = ((unsigned int)u) << 16;
    return x.f;
}
__device__ __forceinline__ float bflo(unsigned int v) { return bf2f((unsigned short)(v & 0xffffu)); }
__device__ __forceinline__ float bfhi(unsigned int v) { return bf2f((unsigned short)(v >> 16)); }
__device__ __forceinline__ unsigned cvtpk(float lo, float hi) {
    unsigned r;
    asm("v_cvt_pk_bf16_f32 %0, %1, %2" : "=v"(r) : "v"(lo), "v"(hi));
    return r;
}

// -------- fused init: conv_x | prep_w | zero bcnt --------
__global__ __launch_bounds__(256) void init_all(const float* __restrict__ x,
                                                unsigned short* __restrict__ h0,
                                                unsigned short* __restrict__ h1,
                                                const float* __restrict__ W1,
                                                const float* __restrict__ W2,
                                                unsigned short* __restrict__ wbf,
                                                int* __restrict__ bcnt) {
    int bb = blockIdx.x;
    if (bb < CONV_BLKS) {
        long long t = (long long)bb * 256 + threadIdx.x;
        long long base = t * 4;
        if (base < (long long)NN * DD) {
            float4 v = *reinterpret_cast<const float4*>(x + base);
            ushort4 p;
            p.x = f2bf(v.x); p.y = f2bf(v.y); p.z = f2bf(v.z); p.w = f2bf(v.w);
            *reinterpret_cast<ushort4*>(h0 + base) = p;
        } else if (base < (long long)(NN + 1) * DD) {
            ushort4 z = {0, 0, 0, 0};
            *reinterpret_cast<ushort4*>(h0 + base) = z;
            *reinterpret_cast<ushort4*>(h1 + base) = z;
        }
        return;
    }
    bb -= CONV_BLKS;
    if (bb < PREPW_BLKS) {
        int idx = bb * 256 + threadIdx.x;            // < NL*2*DD*DD
        int k = idx & 127;
        int n = (idx >> 7) & 127;
        int w = (idx >> 14) & 1;
        int l = idx >> 15;
        const float* src = w ? W2 : W1;
        wbf[idx] = f2bf(src[(l * DD + k) * DD + n]);
        return;
    }
    // last block: zero bucket counters
    int i = threadIdx.x;
    if (i < NBUCK2) bcnt[i] = 0;
}

// ---------------- CSR build (bucket-first, no per-node global atomics) ----------------
// block-staged coarse-bucket histogram: LDS hist + one global add per (block,bucket)
__global__ __launch_bounds__(256) void bcount(const int* __restrict__ ei,
                                              int* __restrict__ bcnt) {
    __shared__ int hist[NBUCK2];
    int tid = threadIdx.x;
    int e0 = blockIdx.x * ECHUNK;
    for (int i = tid; i < NBUCK2; i += 256) hist[i] = 0;
    __syncthreads();
    for (int i = tid; i < ECHUNK; i += 256)
        atomicAdd(&hist[ei[NE + e0 + i] >> BSHIFT], 1);
    __syncthreads();
    for (int i = tid; i < NBUCK2; i += 256) {
        int h = hist[i];
        if (h) atomicAdd(&bcnt[i], h);
    }
}

// exclusive scan bcnt -> cboff; zero gpos
__global__ __launch_bounds__(256) void bscan(const int* __restrict__ bcnt,
                                             int* __restrict__ cboff,
                                             int* __restrict__ gpos) {
    __shared__ int s[256];
    int tid = threadIdx.x;
    int sum = (tid < NBUCK2) ? bcnt[tid] : 0;
    s[tid] = sum;
    __syncthreads();
    for (int o = 1; o < 256; o <<= 1) {
        int t = (tid >= o) ? s[tid - o] : 0;
        __syncthreads();
        s[tid] += t;
        __syncthreads();
    }
    if (tid < NBUCK2) {
        cboff[tid] = s[tid] - sum;
        gpos[tid] = 0;
    }
    if (tid == 0) cboff[NBUCK2] = NE;
}

// pass A: block-staged binning. LDS histogram -> one global reservation per
// (block,bucket) -> scatter as contiguous runs. Packed: src | dlocal<<17.
__global__ __launch_bounds__(256) void binA(const int* __restrict__ ei,
                                            const int* __restrict__ cboff,
                                            int* __restrict__ gpos,
                                            int* __restrict__ ebuf) {
    __shared__ int hist[NBUCK2];
    __shared__ int sbase[NBUCK2];
    int tid = threadIdx.x;
    int e0 = blockIdx.x * ECHUNK;
    for (int i = tid; i < NBUCK2; i += 256) hist[i] = 0;
    __syncthreads();
    for (int i = tid; i < ECHUNK; i += 256) {
        int d = ei[NE + e0 + i];
        atomicAdd(&hist[d >> BSHIFT], 1);
    }
    __syncthreads();
    for (int i = tid; i < NBUCK2; i += 256) {
        int h = hist[i];
        sbase[i] = (h > 0) ? atomicAdd(&gpos[i], h) : 0;
        hist[i] = 0;    // reuse as cursor
    }
    __syncthreads();
    for (int i = tid; i < ECHUNK; i += 256) {
        int s2 = ei[e0 + i];
        int d = ei[NE + e0 + i];
        int b = d >> BSHIFT;
        int pos = atomicAdd(&hist[b], 1);
        ebuf[cboff[b] + sbase[b] + pos] = s2 | ((d & 511) << 17);
    }
}

// per bucket: count degrees from own ebuf segment (LDS), padded local prefix
// -> rp (bucket-local), bucket padded total -> bsum
__global__ __launch_bounds__(256) void bpre(const int* __restrict__ ebuf,
                                            const int* __restrict__ cboff,
                                            int* __restrict__ rp,
                                            int* __restrict__ bsum) {
    __shared__ int lcnt[512];
    __shared__ int s[256];
    int b = blockIdx.x;
    int tid = threadIdx.x;
    lcnt[tid] = 0;
    lcnt[tid + 256] = 0;
    __syncthreads();
    int st = cboff[b], en = cboff[b + 1];
    for (int i = st + tid; i < en; i += 256)
        atomicAdd(&lcnt[ebuf[i] >> 17], 1);
    __syncthreads();
    int d0 = (lcnt[2 * tid] + 7) & ~7;
    int d1 = (lcnt[2 * tid + 1] + 7) & ~7;
    int ps = d0 + d1;
    s[tid] = ps;
    __syncthreads();
    for (int o = 1; o < 256; o <<= 1) {
        int t = (tid >= o) ? s[tid - o] : 0;
        __syncthreads();
        s[tid] += t;
        __syncthreads();
    }
    int base = s[tid] - ps;   // exclusive over pairs
    int node0 = (b << BSHIFT) + 2 * tid;
    if (node0 < NN) rp[node0] = base;
    if (node0 + 1 < NN) rp[node0 + 1] = base + d0;
    if (tid == 255) bsum[b] = s[255];
}

// scan bsum -> bbase (exclusive); rp[NN] = total padded size
__global__ __launch_bounds__(256) void bscan2(const int* __restrict__ bsum,
                                              int* __restrict__ bbase,
                                              int* __restrict__ rp) {
    __shared__ int s[256];
    int tid = threadIdx.x;
    int sum = (tid < NBUCK2) ? bsum[tid] : 0;
    s[tid] = sum;
    __syncthreads();
    for (int o = 1; o < 256; o <<= 1) {
        int t = (tid >= o) ? s[tid - o] : 0;
        __syncthreads();
        s[tid] += t;
        __syncthreads();
    }
    if (tid < NBUCK2) bbase[tid] = s[tid] - sum;
    if (tid == 255) rp[NN] = s[255];
}

// per bucket: finalize rp (+= bbase), place edges via LDS cursors, write pads
__global__ __launch_bounds__(256) void binB2(const int* __restrict__ ebuf,
                                             const int* __restrict__ cboff,
                                             const int* __restrict__ bbase,
                                             int* __restrict__ rp,
                                             int* __restrict__ csr) {
    __shared__ int rpl[512];
    __shared__ int lcnt[512];
    int b = blockIdx.x;
    int tid = threadIdx.x;
    int bb = bbase[b];
    for (int i = tid; i < 512; i += 256) {
        int node = (b << BSHIFT) + i;
        int v = 0;
        if (node < NN) {
            v = rp[node] + bb;
            rp[node] = v;
        }
        rpl[i] = v;
        lcnt[i] = 0;
    }
    __syncthreads();
    int st = cboff[b], en = cboff[b + 1];
    for (int i = st + tid; i < en; i += 256) {
        int v = ebuf[i];
        int dl = v >> 17;
        int pos = atomicAdd(&lcnt[dl], 1);
        csr[rpl[dl] + pos] = v & 0x1FFFF;
    }
    __syncthreads();
    for (int i = tid; i < 512; i += 256) {
        int node = (b << BSHIFT) + i;
        if (node >= NN) continue;
        int d = lcnt[i];
        int pd = (d + 7) & ~7;
        int base = rpl[i];
        for (int j = d; j < pd; ++j) csr[base + j] = NN;
    }
}

// ---------------- fused layer: gather-agg + MLP + BN ----------------
__global__ __launch_bounds__(256) void layer_fused(
    const unsigned short* __restrict__ hin,   // (NN+1) rows, row NN = zeros
    const int* __restrict__ rp,               // padded row ptr (8-aligned)
    const int* __restrict__ csr,              // padded neighbor lists
    const unsigned short* __restrict__ w1t,   // [n][k] bf16
    const unsigned short* __restrict__ w2t,   // [n][k] bf16
    const float* __restrict__ b1,
    const float* __restrict__ b2,
    const float* __restrict__ gamma,
    const float* __restrict__ beta,
    const float* __restrict__ rmean,
    const float* __restrict__ rvar,
    const float* __restrict__ epsv,
    unsigned short* __restrict__ hout)
{
    __shared__ unsigned short z_lds[16 * 136];   // 4.35 KB
    const int tid = threadIdx.x;
    const int lane = tid & 63;
    const int wave = tid >> 6;
    const int gid = lane >> 4;        // group 0..3, owns one row
    const int lg = lane & 15;         // 16B feature slice within group
    const int row0 = blockIdx.x * 16;
    const float epl = 1.0f + epsv[0];
    const size_t lgo = (size_t)lg * 8;

#define ACC8(v) do { \
    acc[0] += bflo((v).x); acc[1] += bfhi((v).x); \
    acc[2] += bflo((v).y); acc[3] += bfhi((v).y); \
    acc[4] += bflo((v).z); acc[5] += bfhi((v).z); \
    acc[6] += bflo((v).w); acc[7] += bfhi((v).w); } while (0)

    // Phase 1: gather-aggregate; group g of wave w owns row w*4+g
    const int rbase = row0 + (wave << 2);
    int pv = (lane < 5) ? rp[rbase + lane] : 0;   // 5 rowptrs
    const int st = __shfl(pv, gid);
    const int en = __shfl(pv, gid + 1);
    const int myrow = rbase + gid;

    float acc[8];
    {
        uint4 sv = *reinterpret_cast<const uint4*>(hin + (size_t)myrow * DD + lgo);
        acc[0] = epl * bflo(sv.x); acc[1] = epl * bfhi(sv.x);
        acc[2] = epl * bflo(sv.y); acc[3] = epl * bfhi(sv.y);
        acc[4] = epl * bflo(sv.z); acc[5] = epl * bfhi(sv.z);
        acc[6] = epl * bflo(sv.w); acc[7] = epl * bfhi(sv.w);
    }
    int c0 = st;
    for (; c0 + 16 <= en; c0 += 16) {
        int4 idA = *reinterpret_cast<const int4*>(csr + c0);
        int4 idB = *reinterpret_cast<const int4*>(csr + c0 + 4);
        int4 idC = *reinterpret_cast<const int4*>(csr + c0 + 8);
        int4 idD = *reinterpret_cast<const int4*>(csr + c0 + 12);
        uint4 v0 = *reinterpret_cast<const uint4*>(hin + (size_t)idA.x * DD + lgo);
        uint4 v1 = *reinterpret_cast<const uint4*>(hin + (size_t)idA.y * DD + lgo);
        uint4 v2 = *reinterpret_cast<const uint4*>(hin + (size_t)idA.z * DD + lgo);
        uint4 v3 = *reinterpret_cast<const uint4*>(hin + (size_t)idA.w * DD + lgo);
        uint4 v4 = *reinterpret_cast<const uint4*>(hin + (size_t)idB.x * DD + lgo);
        uint4 v5 = *reinterpret_cast<const uint4*>(hin + (size_t)idB.y * DD + lgo);
        uint4 v6 = *reinterpret_cast<const uint4*>(hin + (size_t)idB.z * DD + lgo);
        uint4 v7 = *reinterpret_cast<const uint4*>(hin + (size_t)idB.w * DD + lgo);
        uint4 v8 = *reinterpret_cast<const uint4*>(hin + (size_t)idC.x * DD + lgo);
        uint4 v9 = *reinterpret_cast<const uint4*>(hin + (size_t)idC.y * DD + lgo);
        uint4 va = *reinterpret_cast<const uint4*>(hin + (size_t)idC.z * DD + lgo);
        uint4 vb = *reinterpret_cast<const uint4*>(hin + (size_t)idC.w * DD + lgo);
        uint4 vc = *reinterpret_cast<const uint4*>(hin + (size_t)idD.x * DD + lgo);
        uint4 vd = *reinterpret_cast<const uint4*>(hin + (size_t)idD.y * DD + lgo);
        uint4 ve = *reinterpret_cast<const uint4*>(hin + (size_t)idD.z * DD + lgo);
        uint4 vf = *reinterpret_cast<const uint4*>(hin + (size_t)idD.w * DD + lgo);
        ACC8(v0); ACC8(v1); ACC8(v2); ACC8(v3);
        ACC8(v4); ACC8(v5); ACC8(v6); ACC8(v7);
        ACC8(v8); ACC8(v9); ACC8(va); ACC8(vb);
        ACC8(vc); ACC8(vd); ACC8(ve); ACC8(vf);
    }
    if (c0 < en) {   // 8-tail (pdeg is a multiple of 8)
        int4 idA = *reinterpret_cast<const int4*>(csr + c0);
        int4 idB = *reinterpret_cast<const int4*>(csr + c0 + 4);
        uint4 v0 = *reinterpret_cast<const uint4*>(hin + (size_t)idA.x * DD + lgo);
        uint4 v1 = *reinterpret_cast<const uint4*>(hin + (size_t)idA.y * DD + lgo);
        uint4 v2 = *reinterpret_cast<const uint4*>(hin + (size_t)idA.z * DD + lgo);
        uint4 v3 = *reinterpret_cast<const uint4*>(hin + (size_t)idA.w * DD + lgo);
        uint4 v4 = *reinterpret_cast<const uint4*>(hin + (size_t)idB.x * DD + lgo);
        uint4 v5 = *reinterpret_cast<const uint4*>(hin + (size_t)idB.y * DD + lgo);
        uint4 v6 = *reinterpret_cast<const uint4*>(hin + (size_t)idB.z * DD + lgo);
        uint4 v7 = *reinterpret_cast<const uint4*>(hin + (size_t)idB.w * DD + lgo);
        ACC8(v0); ACC8(v1); ACC8(v2); ACC8(v3);
        ACC8(v4); ACC8(v5); ACC8(v6); ACC8(v7);
    }
    {
        uint4 pk;
        pk.x = cvtpk(acc[0], acc[1]);
        pk.y = cvtpk(acc[2], acc[3]);
        pk.z = cvtpk(acc[4], acc[5]);
        pk.w = cvtpk(acc[6], acc[7]);
        *reinterpret_cast<uint4*>(&z_lds[((wave << 2) + gid) * 136 + lg * 8]) = pk;
    }
    __syncthreads();

    const int l15 = lane & 15;
    const int kq = lane >> 4;
    const int colbase = wave << 5;     // 32-col slice per wave

    // afr reads of z tile, then barrier (lets epi1 overlap others' MFMA1)
    bf16x8 afr[4];
    #pragma unroll
    for (int kk = 0; kk < 4; ++kk)
        afr[kk] = *reinterpret_cast<const bf16x8*>(&z_lds[l15 * 136 + kk * 32 + kq * 8]);
    __syncthreads();

    // Matmul 1 (B-fragments straight from global; 32 KB weight is L1/L2-hot)
    f32x4 acc4[2];
    #pragma unroll
    for (int nt = 0; nt < 2; ++nt) acc4[nt] = (f32x4){0.f, 0.f, 0.f, 0.f};
    #pragma unroll
    for (int nt = 0; nt < 2; ++nt) {
        #pragma unroll
        for (int kk = 0; kk < 4; ++kk) {
            bf16x8 bfr = *reinterpret_cast<const bf16x8*>(
                w1t + (colbase + nt * 16 + l15) * DD + kk * 32 + kq * 8);
            acc4[nt] = __builtin_amdgcn_mfma_f32_16x16x32_bf16(afr[kk], bfr, acc4[nt], 0, 0, 0);
        }
    }

    // Epilogue 1: bias+relu, z1 -> z_lds (own 32-col slice, rows 0..15)
    #pragma unroll
    for (int nt = 0; nt < 2; ++nt) {
        int col = colbase + nt * 16 + l15;
        float bv = b1[col];
        #pragma unroll
        for (int r = 0; r < 4; ++r) {
            int zr = kq * 4 + r;
            float v = acc4[nt][r] + bv;
            v = v > 0.f ? v : 0.f;
            z_lds[zr * 136 + col] = f2bf(v);
        }
    }
    __syncthreads();

    // Matmul 2
    #pragma unroll
    for (int kk = 0; kk < 4; ++kk)
        afr[kk] = *reinterpret_cast<const bf16x8*>(&z_lds[l15 * 136 + kk * 32 + kq * 8]);
    #pragma unroll
    for (int nt = 0; nt < 2; ++nt) acc4[nt] = (f32x4){0.f, 0.f, 0.f, 0.f};
    #pragma unroll
    for (int nt = 0; nt < 2; ++nt) {
        #pragma unroll
        for (int kk = 0; kk < 4; ++kk) {
            bf16x8 bfr = *reinterpret_cast<const bf16x8*>(
                w2t + (colbase + nt * 16 + l15) * DD + kk * 32 + kq * 8);
            acc4[nt] = __builtin_amdgcn_mfma_f32_16x16x32_bf16(afr[kk], bfr, acc4[nt], 0, 0, 0);
        }
    }

    // Epilogue 2: bias+relu+BN -> hout (bf16); rows always < NN (no tail)
    #pragma unroll
    for (int nt = 0; nt < 2; ++nt) {
        int col = colbase + nt * 16 + l15;
        float bv = b2[col];
        float ga = gamma[col];
        float be = beta[col];
        float mu = rmean[col];
        float inv = rsqrtf(rvar[col] + 1e-5f);
        #pragma unroll
        for (int r = 0; r < 4; ++r) {
            int zr = kq * 4 + r;
            float v = acc4[nt][r] + bv;
            v = v > 0.f ? v : 0.f;
            v = (v - mu) * inv * ga + be;
            hout[(size_t)(row0 + zr) * DD + col] = f2bf(v);
        }
    }
#undef ACC8
}

// ---------------- pool (sorted batch -> segment sums) + final linear ----------------
__global__ __launch_bounds__(256) void pool_final(const unsigned short* __restrict__ h,
                                                  const int* __restrict__ batch,
                                                  const float* __restrict__ W,
                                                  const float* __restrict__ b,
                                                  float* __restrict__ out) {
    int g = blockIdx.x;           // one block per graph
    int t = threadIdx.x;
    int c2 = t & 63;              // col pair 2*c2, 2*c2+1
    int qu = t >> 6;              // row strand 0..3

    int lo = 0, hi = NN;
    while (lo < hi) { int mid = (lo + hi) >> 1; if (batch[mid] < g) lo = mid + 1; else hi = mid; }
    int start = lo;
    hi = NN;
    while (lo < hi) { int mid = (lo + hi) >> 1; if (batch[mid] < g + 1) lo = mid + 1; else hi = mid; }
    int end = lo;

    float ax = 0.f, ay = 0.f;
    for (int i = start + qu; i < end; i += 4) {
        unsigned u = *reinterpret_cast<const unsigned*>(h + (size_t)i * DD + c2 * 2);
        ax += bflo(u); ay += bfhi(u);
    }

    __shared__ float ps[4][DD];
    ps[qu][c2 * 2] = ax;
    ps[qu][c2 * 2 + 1] = ay;
    __syncthreads();
    if (t < DD) {
        float inv = 1.0f / fmaxf((float)(end - start), 1.0f);
        ps[0][t] = (ps[0][t] + ps[1][t] + ps[2][t] + ps[3][t]) * inv;
    }
    __syncthreads();
    if (t < DD) {
        float o = b[t];
        #pragma unroll 8
        for (int k = 0; k < DD; ++k)
            o += ps[0][k] * W[k * DD + t];
        out[(size_t)g * DD + t] = fmaxf(o, 0.f);
    }
}

extern "C" void kernel_launch(void* const* d_in, const int* in_sizes, int n_in,
                              void* d_out, int out_size, void* d_ws, size_t ws_size,
                              hipStream_t stream) {
    const float* x     = (const float*)d_in[0];
    const int*   ei    = (const int*)d_in[1];
    const int*   batch = (const int*)d_in[2];
    const float* W1    = (const float*)d_in[3];
    const float* b1    = (const float*)d_in[4];
    const float* W2    = (const float*)d_in[5];
    const float* b2    = (const float*)d_in[6];
    const float* gamma = (const float*)d_in[7];
    const float* beta  = (const float*)d_in[8];
    const float* rmean = (const float*)d_in[9];
    const float* rvar  = (const float*)d_in[10];
    const float* eps   = (const float*)d_in[11];
    const float* lin1W = (const float*)d_in[12];
    const float* lin1b = (const float*)d_in[13];
    float* out = (float*)d_out;

    char* ws = (char*)d_ws;
    size_t off = 0;
    auto alloc = [&](size_t bytes) {
        void* p = ws + off;
        off = (off + bytes + 255) & ~(size_t)255;
        return p;
    };
    unsigned short* h0  = (unsigned short*)alloc((size_t)(NN + 1) * DD * 2);
    unsigned short* h1  = (unsigned short*)alloc((size_t)(NN + 1) * DD * 2);
    int* rp    = (int*)alloc((size_t)(NN + 1) * 4);
    int* bcnt  = (int*)alloc((size_t)NBUCK2 * 4);
    int* cboff = (int*)alloc((size_t)(NBUCK2 + 1) * 4);
    int* gpos  = (int*)alloc((size_t)NBUCK2 * 4);
    int* bsum  = (int*)alloc((size_t)NBUCK2 * 4);
    int* bbase = (int*)alloc((size_t)NBUCK2 * 4);
    int* csr   = (int*)alloc((size_t)CSRP * 4);
    int* ebuf  = (int*)alloc((size_t)NE * 4);
    unsigned short* wbf = (unsigned short*)alloc((size_t)NL * 2 * DD * DD * 2);

    init_all<<<INIT_BLKS, 256, 0, stream>>>(x, h0, h1, W1, W2, wbf, bcnt);

    bcount<<<ABLKS, 256, 0, stream>>>(ei, bcnt);
    bscan<<<1, 256, 0, stream>>>(bcnt, cboff, gpos);
    binA<<<ABLKS, 256, 0, stream>>>(ei, cboff, gpos, ebuf);
    bpre<<<NBUCK2, 256, 0, stream>>>(ebuf, cboff, rp, bsum);
    bscan2<<<1, 256, 0, stream>>>(bsum, bbase, rp);
    binB2<<<NBUCK2, 256, 0, stream>>>(ebuf, cboff, bbase, rp, csr);

    const int lgrid = NN / 16;   // 6250, exact
    layer_fused<<<lgrid, 256, 0, stream>>>(
        h0, rp, csr, wbf + 0 * DD * DD, wbf + 1 * DD * DD,
        b1 + 0 * DD, b2 + 0 * DD, gamma + 0 * DD, beta + 0 * DD,
        rmean + 0 * DD, rvar + 0 * DD, eps + 0, h1);
    layer_fused<<<lgrid, 256, 0, stream>>>(
        h1, rp, csr, wbf + 2 * DD * DD, wbf + 3 * DD * DD,
        b1 + 1 * DD, b2 + 1 * DD, gamma + 1 * DD, beta + 1 * DD,
        rmean + 1 * DD, rvar + 1 * DD, eps + 1, h0);
    layer_fused<<<lgrid, 256, 0, stream>>>(
        h0, rp, csr, wbf + 4 * DD * DD, wbf + 5 * DD * DD,
        b1 + 2 * DD, b2 + 2 * DD, gamma + 2 * DD, beta + 2 * DD,
        rmean + 2 * DD, rvar + 2 * DD, eps + 2, h1);

    pool_final<<<NG, 256, 0, stream>>>(h1, batch, lin1W, lin1b, out);
}